// Round 2
// baseline (655.652 us; speedup 1.0000x reference)
//
#include <hip/hip_runtime.h>
#include <math.h>

#define TT 8192   // tokens = B*P
#define NE 8      // experts
#define DIN 1024  // input size
#define DH 512    // hidden size
#define MT_MAX 136  // ceil(2*TT/128) + NE  (padded m-tiles upper bound)

typedef __attribute__((ext_vector_type(8))) short short8;   // 8 bf16 = 4 VGPRs
typedef __attribute__((ext_vector_type(4))) float f32x4;
typedef __attribute__((ext_vector_type(4))) unsigned short us4;

// ---------------- workspace layout (bytes) ----------------
static const size_t OFF_BASE   = 0;                                      // int[9] padded prefix
static const size_t OFF_TOKEXP = 256;                                    // int2[TT]
static const size_t OFF_GPAIR  = OFF_TOKEXP + (size_t)TT * 8;            // float2[TT]
static const size_t OFF_TOK    = OFF_GPAIR  + (size_t)TT * 8;            // int[2*TT+NE*128]
static const size_t OFF_GATE   = OFF_TOK    + (size_t)(2 * TT + NE * 128) * 4; // float[...]
static const size_t OFF_XB     = OFF_GATE   + (size_t)(2 * TT + NE * 128) * 4; // bf16[TT][DIN]
static const size_t OFF_W1T    = OFF_XB     + (size_t)TT * DIN * 2;      // bf16[NE][DH][DIN]
static const size_t OFF_W2T    = OFF_W1T    + (size_t)NE * DH * DIN * 2; // bf16[NE][DIN][DH]
static const size_t OFF_H      = OFF_W2T    + (size_t)NE * DIN * DH * 2; // bf16[MT_MAX*128][DH]

__device__ __forceinline__ unsigned short f2bf(float f) {
    union { float f; unsigned u; } v; v.f = f;
    unsigned r = (v.u + 0x7fffu + ((v.u >> 16) & 1u)) >> 16;
    return (unsigned short)r;
}
__device__ __forceinline__ void async_copy16(const void* g, void* l) {
    __builtin_amdgcn_global_load_lds(
        (const __attribute__((address_space(1))) void*)g,
        (__attribute__((address_space(3))) void*)l, 16, 0, 0);
}

// exact-erf GELU via Abramowitz-Stegun 7.1.26 (|err| <= 1.5e-7, << bf16 ulp)
__device__ __forceinline__ float gelu_erf(float u) {
    float z  = 0.70710678118f * u;
    float az = fabsf(z);
    float t  = __builtin_amdgcn_rcpf(__builtin_fmaf(0.3275911f, az, 1.0f));
    float p  = t * (0.254829592f + t * (-0.284496736f + t * (1.421413741f +
               t * (-1.453152027f + t * 1.061405429f))));
    float e2 = exp2f(-1.4426950408889634f * az * az);
    float er = __builtin_fmaf(-p, e2, 1.0f);
    er = copysignf(er, z);
    return 0.5f * u * (1.0f + er);
}

// ---------------- fused prep: gate | zero-out | convert x | transpose w1/w2 -------------
// grid: [0,2048) gate | [2048,4096) zero out | [4096,8192) x | [8192,12288) w1 | [12288,16384) w2
__global__ __launch_bounds__(256) void prep_kernel(
    const float* __restrict__ x, const float* __restrict__ w1, const float* __restrict__ w2,
    const float* __restrict__ Q, const float* __restrict__ Kc,
    unsigned short* __restrict__ xb, unsigned short* __restrict__ w1t,
    unsigned short* __restrict__ w2t,
    int2* __restrict__ tokexp, float2* __restrict__ gpair,
    float* __restrict__ out)
{
    __shared__ float tile[32][33];
    int bid = blockIdx.x;
    int tid = threadIdx.x;

    if (bid < 2048) {
        // ---- gating: one wave per token (long-pole blocks dispatched first) ----
        int wave = tid >> 6, lane = tid & 63;
        int t = bid * 4 + wave;
        const float4* q4 = reinterpret_cast<const float4*>(Q + (size_t)t * DIN);
        const float4* k4 = reinterpret_cast<const float4*>(Kc + (size_t)t * NE * DIN);
        float4 q[4];
#pragma unroll
        for (int j = 0; j < 4; ++j) q[j] = q4[j * 64 + lane];
        float part[NE];
#pragma unroll
        for (int e = 0; e < NE; ++e) {
            float s = 0.0f;
#pragma unroll
            for (int j = 0; j < 4; ++j) {
                float4 kv = k4[e * 256 + j * 64 + lane];
                s += q[j].x * kv.x + q[j].y * kv.y + q[j].z * kv.z + q[j].w * kv.w;
            }
            part[e] = s;
        }
#pragma unroll
        for (int e = 0; e < NE; ++e) {
#pragma unroll
            for (int m = 1; m < 64; m <<= 1) part[e] += __shfl_xor(part[e], m);
        }
        if (lane == 0) {
            float s[NE];
#pragma unroll
            for (int e = 0; e < NE; ++e) {
                float v = part[e] * 0.03125f;
                if (isnan(v)) v = 0.0f;
                else if (isinf(v)) v = (v > 0.0f) ? 20.0f : -20.0f;
                s[e] = v;
            }
            float m = s[0];
            for (int e = 1; e < NE; ++e) m = fmaxf(m, s[e]);
            float p[NE]; float sum = 0.0f;
            for (int e = 0; e < NE; ++e) { p[e] = expf(s[e] - m); sum += p[e]; }
            float inv = 1.0f / sum;
            for (int e = 0; e < NE; ++e) p[e] *= inv;
            int i0 = 0;
            for (int e = 1; e < NE; ++e) if (p[e] > p[i0]) i0 = e;
            int i1 = (i0 == 0) ? 1 : 0;
            for (int e = 0; e < NE; ++e) if (e != i0 && p[e] > p[i1]) i1 = e;
            float denom = p[i0] + p[i1] + 1e-6f;
            tokexp[t] = make_int2(i0, i1);
            gpair[t]  = make_float2(p[i0] / denom, p[i1] / denom);
        }
    } else if (bid < 4096) {
        // ---- zero out: gemm2 accumulates into it atomically ----
        size_t i = ((size_t)(bid - 2048) * 256 + tid) * 16;
        float4 z = {0.f, 0.f, 0.f, 0.f};
#pragma unroll
        for (int j = 0; j < 4; ++j)
            *reinterpret_cast<float4*>(out + i + j * 4) = z;
    } else if (bid < 8192) {
        // ---- convert x: fp32 -> bf16, 8 elems/thread ----
        size_t i = ((size_t)(bid - 4096) * 256 + tid) * 8;
        float4 a = *reinterpret_cast<const float4*>(x + i);
        float4 b = *reinterpret_cast<const float4*>(x + i + 4);
        us4 o0 = { f2bf(a.x), f2bf(a.y), f2bf(a.z), f2bf(a.w) };
        us4 o1 = { f2bf(b.x), f2bf(b.y), f2bf(b.z), f2bf(b.w) };
        *reinterpret_cast<us4*>(xb + i)     = o0;
        *reinterpret_cast<us4*>(xb + i + 4) = o1;
    } else {
        // ---- transpose+convert weights: src [E][K][N] fp32 -> dst [E][N][K] bf16 ----
        const float* src; unsigned short* dst; int K, N, e, k0, n0;
        if (bid < 12288) {
            int r = bid - 8192; e = r >> 9; int rem = r & 511;
            k0 = (rem & 31) * 32; n0 = (rem >> 5) * 32;
            src = w1; dst = w1t; K = DIN; N = DH;
        } else {
            int r = bid - 12288; e = r >> 9; int rem = r & 511;
            k0 = (rem & 15) * 32; n0 = (rem >> 4) * 32;
            src = w2; dst = w2t; K = DH; N = DIN;
        }
        int tx = tid & 31, ty = tid >> 5;
        const float* s = src + ((size_t)e * K + k0) * N + n0;
#pragma unroll
        for (int r2 = 0; r2 < 32; r2 += 8) tile[ty + r2][tx] = s[(size_t)(ty + r2) * N + tx];
        __syncthreads();
        unsigned short* d = dst + ((size_t)e * N + n0) * K + k0;
#pragma unroll
        for (int r2 = 0; r2 < 32; r2 += 8) d[(size_t)(ty + r2) * K + tx] = f2bf(tile[tx][ty + r2]);
    }
}

// ---------------- routing: histogram + 128-aligned prefix + padded build ----------------
__global__ __launch_bounds__(1024) void route_kernel(
    const int2* __restrict__ tokexp, const float2* __restrict__ gpair,
    int* __restrict__ base,
    int* __restrict__ tok_list, float* __restrict__ gate_list)
{
    int e = blockIdx.x;
    int tid = threadIdx.x;
    int wave = tid >> 6, lane = tid & 63;
    __shared__ int hist[NE];
    __shared__ int wsum[16];
    __shared__ int running;

    if (tid < NE) hist[tid] = 0;
    __syncthreads();

    // full histogram (every block computes all 8 counts)
    int lc[NE];
#pragma unroll
    for (int j = 0; j < NE; ++j) lc[j] = 0;
#pragma unroll
    for (int r = 0; r < TT / 1024; ++r) {
        int2 te = tokexp[r * 1024 + tid];
#pragma unroll
        for (int j = 0; j < NE; ++j) lc[j] += (te.x == j ? 1 : 0) + (te.y == j ? 1 : 0);
    }
#pragma unroll
    for (int j = 0; j < NE; ++j) {
        int v = lc[j];
#pragma unroll
        for (int m = 1; m < 64; m <<= 1) v += __shfl_xor(v, m);
        if (lane == 0) atomicAdd(&hist[j], v);
    }
    __syncthreads();

    // 128-aligned prefix (identical in every block)
    int basep[NE + 1];
    basep[0] = 0;
#pragma unroll
    for (int j = 0; j < NE; ++j) basep[j + 1] = basep[j] + ((hist[j] + 127) & ~127);

    if (tid == 0) {
        base[e] = basep[e];
        if (e == 0) base[NE] = basep[NE];
        running = basep[e];
    }
    __syncthreads();

    int myb = basep[e];
    int cnt_e = hist[e];
#pragma unroll 1
    for (int r = 0; r < TT / 1024; ++r) {
        int t = r * 1024 + tid;
        int2 te = tokexp[t];
        float2 g = gpair[t];
        bool f0 = (te.x == e), f1 = (te.y == e);
        bool f = f0 || f1;
        unsigned long long mask = __ballot(f);
        int mypos = __popcll(mask & ((1ull << lane) - 1ull));
        if (lane == 0) wsum[wave] = __popcll(mask);
        __syncthreads();
        int off = 0, total = 0;
        for (int w = 0; w < 16; ++w) {
            int c = wsum[w];
            if (w < wave) off += c;
            total += c;
        }
        int pos = running + off + mypos;
        if (f) {
            tok_list[pos]  = t;
            gate_list[pos] = f0 ? g.x : g.y;
        }
        __syncthreads();
        if (tid == 0) running += total;
        __syncthreads();
    }

    // pad slots: token 0 with gate 0 (safe rows, zero contribution)
    int padn = ((cnt_e + 127) & ~127) - cnt_e;
    if (tid < padn) {
        tok_list[myb + cnt_e + tid]  = 0;
        gate_list[myb + cnt_e + tid] = 0.0f;
    }
}

// ---------------- GEMM1: h = gelu(gather(xb) @ w1t^T), BK=64, double-buffered -----------
__global__ __launch_bounds__(256) void gemm1_kernel(
    const unsigned short* __restrict__ xb, const unsigned short* __restrict__ w1t,
    const int* __restrict__ base,
    const int* __restrict__ tok_list, unsigned short* __restrict__ h)
{
    int bv[NE + 1];
#pragma unroll
    for (int i = 0; i <= NE; ++i) bv[i] = base[i];
    int g0 = blockIdx.x * 128;
    if (g0 >= bv[NE]) return;
    int e = 0;
#pragma unroll
    for (int i = 1; i < NE; ++i) if (g0 >= bv[i]) e = i;

    int n0 = blockIdx.y * 128;

    __shared__ __align__(16) char smem[65536];   // 2 buffers x [A 16K | B 16K]

    int tid = threadIdx.x;
    int w = tid >> 6, lane = tid & 63;
    int wm = w & 1, wn = w >> 1;
    int mcol = lane & 15;
    int kq = (lane >> 4) * 8;

    int ra0 = tok_list[g0 + (2 * w + 0) * 16 + mcol];
    int ra1 = tok_list[g0 + (2 * w + 1) * 16 + mcol];

    const unsigned short* w1e = w1t + (size_t)e * DH * DIN;
    const unsigned short* pa0 = xb + (size_t)ra0 * DIN + kq;
    const unsigned short* pa1 = xb + (size_t)ra1 * DIN + kq;
    const unsigned short* pb0 = w1e + (size_t)(n0 + (2 * w + 0) * 16 + mcol) * DIN + kq;
    const unsigned short* pb1 = w1e + (size_t)(n0 + (2 * w + 1) * 16 + mcol) * DIN + kq;

    int d0 = (2 * w + 0) * 1024;
    int d1 = (2 * w + 1) * 1024;

#define STAGE1(buf, koff) do { \
    async_copy16(pa0 + (koff),      (buf) + d0); \
    async_copy16(pa1 + (koff),      (buf) + d1); \
    async_copy16(pa0 + (koff) + 32, (buf) + 8192  + d0); \
    async_copy16(pa1 + (koff) + 32, (buf) + 8192  + d1); \
    async_copy16(pb0 + (koff),      (buf) + 16384 + d0); \
    async_copy16(pb1 + (koff),      (buf) + 16384 + d1); \
    async_copy16(pb0 + (koff) + 32, (buf) + 24576 + d0); \
    async_copy16(pb1 + (koff) + 32, (buf) + 24576 + d1); \
} while (0)

    f32x4 acc[4][4];
#pragma unroll
    for (int i = 0; i < 4; i++)
#pragma unroll
        for (int j = 0; j < 4; j++) acc[i][j] = {0.f, 0.f, 0.f, 0.f};

    char* cur = smem;
    char* nxt = smem + 32768;

    STAGE1(cur, 0);
    __syncthreads();

    const int NT = DIN / 64;               // 16
    for (int t = 0; t < NT; ++t) {
        if (t + 1 < NT) STAGE1(nxt, (t + 1) * 64);
#pragma unroll
        for (int half = 0; half < 2; ++half) {
            const char* cb = cur + half * 8192;
            short8 af[4], bfr[4];
#pragma unroll
            for (int mt = 0; mt < 4; ++mt)
                af[mt] = *reinterpret_cast<const short8*>(cb + (wm * 4 + mt) * 1024 + lane * 16);
#pragma unroll
            for (int nt = 0; nt < 4; ++nt)
                bfr[nt] = *reinterpret_cast<const short8*>(cb + 16384 + (wn * 4 + nt) * 1024 + lane * 16);
#pragma unroll
            for (int mt = 0; mt < 4; ++mt)
#pragma unroll
                for (int nt = 0; nt < 4; ++nt)
                    acc[mt][nt] = __builtin_amdgcn_mfma_f32_16x16x32_bf16(af[mt], bfr[nt], acc[mt][nt], 0, 0, 0);
        }
        __syncthreads();
        char* tmp = cur; cur = nxt; nxt = tmp;
    }
#undef STAGE1

#pragma unroll
    for (int mt = 0; mt < 4; ++mt) {
        int rbase = (wm * 4 + mt) * 16 + ((lane >> 4) * 4);
#pragma unroll
        for (int r = 0; r < 4; ++r) {
            int row = rbase + r;
#pragma unroll
            for (int nt = 0; nt < 4; ++nt) {
                float g = gelu_erf(acc[mt][nt][r]);
                int col = n0 + (wn * 4 + nt) * 16 + mcol;
                h[(size_t)(g0 + row) * DH + col] = f2bf(g);
            }
        }
    }
}

// ---------------- GEMM2: out[tok] += gate * (h @ w2t^T), atomic f32 ---------------------
__global__ __launch_bounds__(256) void gemm2_kernel(
    const unsigned short* __restrict__ h, const unsigned short* __restrict__ w2t,
    const int* __restrict__ base,
    const int* __restrict__ tok_list, const float* __restrict__ gate_list,
    float* __restrict__ out)
{
    int bv[NE + 1];
#pragma unroll
    for (int i = 0; i <= NE; ++i) bv[i] = base[i];
    int g0 = blockIdx.x * 128;
    if (g0 >= bv[NE]) return;
    int e = 0;
#pragma unroll
    for (int i = 1; i < NE; ++i) if (g0 >= bv[i]) e = i;

    int n0 = blockIdx.y * 128;

    __shared__ __align__(16) char smem[65536];

    int tid = threadIdx.x;
    int w = tid >> 6, lane = tid & 63;
    int wm = w & 1, wn = w >> 1;
    int mcol = lane & 15;
    int kq = (lane >> 4) * 8;

    const unsigned short* w2e = w2t + (size_t)e * DIN * DH;
    const unsigned short* pa0 = h + (size_t)(g0 + (2 * w + 0) * 16 + mcol) * DH + kq;
    const unsigned short* pa1 = h + (size_t)(g0 + (2 * w + 1) * 16 + mcol) * DH + kq;
    const unsigned short* pb0 = w2e + (size_t)(n0 + (2 * w + 0) * 16 + mcol) * DH + kq;
    const unsigned short* pb1 = w2e + (size_t)(n0 + (2 * w + 1) * 16 + mcol) * DH + kq;

    int d0 = (2 * w + 0) * 1024;
    int d1 = (2 * w + 1) * 1024;

#define STAGE2(buf, koff) do { \
    async_copy16(pa0 + (koff),      (buf) + d0); \
    async_copy16(pa1 + (koff),      (buf) + d1); \
    async_copy16(pa0 + (koff) + 32, (buf) + 8192  + d0); \
    async_copy16(pa1 + (koff) + 32, (buf) + 8192  + d1); \
    async_copy16(pb0 + (koff),      (buf) + 16384 + d0); \
    async_copy16(pb1 + (koff),      (buf) + 16384 + d1); \
    async_copy16(pb0 + (koff) + 32, (buf) + 24576 + d0); \
    async_copy16(pb1 + (koff) + 32, (buf) + 24576 + d1); \
} while (0)

    f32x4 acc[4][4];
#pragma unroll
    for (int i = 0; i < 4; i++)
#pragma unroll
        for (int j = 0; j < 4; j++) acc[i][j] = {0.f, 0.f, 0.f, 0.f};

    char* cur = smem;
    char* nxt = smem + 32768;

    STAGE2(cur, 0);
    __syncthreads();

    const int NT = DH / 64;                // 8
    for (int t = 0; t < NT; ++t) {
        if (t + 1 < NT) STAGE2(nxt, (t + 1) * 64);
#pragma unroll
        for (int half = 0; half < 2; ++half) {
            const char* cb = cur + half * 8192;
            short8 af[4], bfr[4];
#pragma unroll
            for (int mt = 0; mt < 4; ++mt)
                af[mt] = *reinterpret_cast<const short8*>(cb + (wm * 4 + mt) * 1024 + lane * 16);
#pragma unroll
            for (int nt = 0; nt < 4; ++nt)
                bfr[nt] = *reinterpret_cast<const short8*>(cb + 16384 + (wn * 4 + nt) * 1024 + lane * 16);
#pragma unroll
            for (int mt = 0; mt < 4; ++mt)
#pragma unroll
                for (int nt = 0; nt < 4; ++nt)
                    acc[mt][nt] = __builtin_amdgcn_mfma_f32_16x16x32_bf16(af[mt], bfr[nt], acc[mt][nt], 0, 0, 0);
        }
        __syncthreads();
        char* tmp = cur; cur = nxt; nxt = tmp;
    }
#undef STAGE2

#pragma unroll
    for (int mt = 0; mt < 4; ++mt) {
        int rbase = (wm * 4 + mt) * 16 + ((lane >> 4) * 4);
#pragma unroll
        for (int r = 0; r < 4; ++r) {
            int row = rbase + r;
            int tok = tok_list[g0 + row];
            float g = gate_list[g0 + row];
#pragma unroll
            for (int nt = 0; nt < 4; ++nt) {
                int col = n0 + (wn * 4 + nt) * 16 + mcol;
                atomicAdd(&out[(size_t)tok * DIN + col], acc[mt][nt][r] * g);
            }
        }
    }
}

extern "C" void kernel_launch(void* const* d_in, const int* in_sizes, int n_in,
                              void* d_out, int out_size, void* d_ws, size_t ws_size,
                              hipStream_t stream) {
    const float* x  = (const float*)d_in[0];
    const float* Q  = (const float*)d_in[1];
    const float* K  = (const float*)d_in[2];
    const float* w1 = (const float*)d_in[3];
    const float* w2 = (const float*)d_in[4];
    float* out = (float*)d_out;

    char* ws = (char*)d_ws;
    int*    base      = (int*)(ws + OFF_BASE);
    int2*   tokexp    = (int2*)(ws + OFF_TOKEXP);
    float2* gpair     = (float2*)(ws + OFF_GPAIR);
    int*    tok_list  = (int*)(ws + OFF_TOK);
    float*  gate_list = (float*)(ws + OFF_GATE);
    unsigned short* xb  = (unsigned short*)(ws + OFF_XB);
    unsigned short* w1t = (unsigned short*)(ws + OFF_W1T);
    unsigned short* w2t = (unsigned short*)(ws + OFF_W2T);
    unsigned short* h   = (unsigned short*)(ws + OFF_H);

    prep_kernel<<<16384, 256, 0, stream>>>(x, w1, w2, Q, K, xb, w1t, w2t, tokexp, gpair, out);
    route_kernel<<<NE, 1024, 0, stream>>>(tokexp, gpair, base, tok_list, gate_list);
    gemm1_kernel<<<dim3(MT_MAX, DH / 128), 256, 0, stream>>>(xb, w1t, base, tok_list, h);
    gemm2_kernel<<<dim3(MT_MAX, DIN / 128), 256, 0, stream>>>(h, w2t, base, tok_list, gate_list, out);
}

// Round 3
// 551.487 us; speedup vs baseline: 1.1889x; 1.1889x over previous
//
#include <hip/hip_runtime.h>
#include <math.h>

#define TT 8192   // tokens = B*P
#define NE 8      // experts
#define DIN 1024  // input size
#define DH 512    // hidden size
#define MT_MAX 136  // ceil(2*TT/128) + NE  (padded m-tiles upper bound)

typedef __attribute__((ext_vector_type(8))) short short8;   // 8 bf16 = 4 VGPRs
typedef __attribute__((ext_vector_type(4))) float f32x4;
typedef __attribute__((ext_vector_type(4))) unsigned short us4;

// ---------------- workspace layout (bytes) ----------------
static const size_t NSLOT      = (size_t)(2 * TT + NE * 128);            // padded slots
static const size_t OFF_BASE   = 0;                                      // int[9] padded prefix
static const size_t OFF_TOKEXP = 256;                                    // int2[TT]
static const size_t OFF_GPAIR  = OFF_TOKEXP + (size_t)TT * 8;            // float2[TT]
static const size_t OFF_SLOT0  = OFF_GPAIR  + (size_t)TT * 8;            // int[TT]
static const size_t OFF_SLOT1  = OFF_SLOT0  + (size_t)TT * 4;            // int[TT]
static const size_t OFF_TOK    = OFF_SLOT1  + (size_t)TT * 4;            // int[NSLOT]
static const size_t OFF_GATE   = OFF_TOK    + NSLOT * 4;                 // float[NSLOT]
static const size_t OFF_XB     = OFF_GATE   + NSLOT * 4;                 // bf16[TT][DIN]
static const size_t OFF_W1T    = OFF_XB     + (size_t)TT * DIN * 2;      // bf16[NE][DH][DIN]
static const size_t OFF_W2T    = OFF_W1T    + (size_t)NE * DH * DIN * 2; // bf16[NE][DIN][DH]
static const size_t OFF_H      = OFF_W2T    + (size_t)NE * DIN * DH * 2; // bf16[NSLOT][DH]
static const size_t OFF_Y      = OFF_H      + NSLOT * DH * 2;            // bf16[NSLOT][DIN]

__device__ __forceinline__ unsigned short f2bf(float f) {
    union { float f; unsigned u; } v; v.f = f;
    unsigned r = (v.u + 0x7fffu + ((v.u >> 16) & 1u)) >> 16;
    return (unsigned short)r;
}
__device__ __forceinline__ float bf2f(unsigned short u) {
    union { unsigned u; float f; } v; v.u = ((unsigned)u) << 16;
    return v.f;
}
__device__ __forceinline__ void async_copy16(const void* g, void* l) {
    __builtin_amdgcn_global_load_lds(
        (const __attribute__((address_space(1))) void*)g,
        (__attribute__((address_space(3))) void*)l, 16, 0, 0);
}

// exact-erf GELU via Abramowitz-Stegun 7.1.26 (|err| <= 1.5e-7, << bf16 ulp)
__device__ __forceinline__ float gelu_erf(float u) {
    float z  = 0.70710678118f * u;
    float az = fabsf(z);
    float t  = __builtin_amdgcn_rcpf(__builtin_fmaf(0.3275911f, az, 1.0f));
    float p  = t * (0.254829592f + t * (-0.284496736f + t * (1.421413741f +
               t * (-1.453152027f + t * 1.061405429f))));
    float e2 = exp2f(-1.4426950408889634f * az * az);
    float er = __builtin_fmaf(-p, e2, 1.0f);
    er = copysignf(er, z);
    return 0.5f * u * (1.0f + er);
}

// ---------------- fused prep: gate | convert x | transpose w1/w2 ------------------------
// grid: [0,2048) gate | [2048,6144) x | [6144,10240) w1 | [10240,14336) w2
__global__ __launch_bounds__(256) void prep_kernel(
    const float* __restrict__ x, const float* __restrict__ w1, const float* __restrict__ w2,
    const float* __restrict__ Q, const float* __restrict__ Kc,
    unsigned short* __restrict__ xb, unsigned short* __restrict__ w1t,
    unsigned short* __restrict__ w2t,
    int2* __restrict__ tokexp, float2* __restrict__ gpair)
{
    __shared__ float tile[32][33];
    int bid = blockIdx.x;
    int tid = threadIdx.x;

    if (bid < 2048) {
        // ---- gating: one wave per token (long-pole blocks dispatched first) ----
        int wave = tid >> 6, lane = tid & 63;
        int t = bid * 4 + wave;
        const float4* q4 = reinterpret_cast<const float4*>(Q + (size_t)t * DIN);
        const float4* k4 = reinterpret_cast<const float4*>(Kc + (size_t)t * NE * DIN);
        float4 q[4];
#pragma unroll
        for (int j = 0; j < 4; ++j) q[j] = q4[j * 64 + lane];
        float part[NE];
#pragma unroll
        for (int e = 0; e < NE; ++e) {
            float s = 0.0f;
#pragma unroll
            for (int j = 0; j < 4; ++j) {
                float4 kv = k4[e * 256 + j * 64 + lane];
                s += q[j].x * kv.x + q[j].y * kv.y + q[j].z * kv.z + q[j].w * kv.w;
            }
            part[e] = s;
        }
#pragma unroll
        for (int e = 0; e < NE; ++e) {
#pragma unroll
            for (int m = 1; m < 64; m <<= 1) part[e] += __shfl_xor(part[e], m);
        }
        if (lane == 0) {
            float s[NE];
#pragma unroll
            for (int e = 0; e < NE; ++e) {
                float v = part[e] * 0.03125f;
                if (isnan(v)) v = 0.0f;
                else if (isinf(v)) v = (v > 0.0f) ? 20.0f : -20.0f;
                s[e] = v;
            }
            float m = s[0];
            for (int e = 1; e < NE; ++e) m = fmaxf(m, s[e]);
            float p[NE]; float sum = 0.0f;
            for (int e = 0; e < NE; ++e) { p[e] = expf(s[e] - m); sum += p[e]; }
            float inv = 1.0f / sum;
            for (int e = 0; e < NE; ++e) p[e] *= inv;
            int i0 = 0;
            for (int e = 1; e < NE; ++e) if (p[e] > p[i0]) i0 = e;
            int i1 = (i0 == 0) ? 1 : 0;
            for (int e = 0; e < NE; ++e) if (e != i0 && p[e] > p[i1]) i1 = e;
            float denom = p[i0] + p[i1] + 1e-6f;
            tokexp[t] = make_int2(i0, i1);
            gpair[t]  = make_float2(p[i0] / denom, p[i1] / denom);
        }
    } else if (bid < 6144) {
        // ---- convert x: fp32 -> bf16, 8 elems/thread ----
        size_t i = ((size_t)(bid - 2048) * 256 + tid) * 8;
        float4 a = *reinterpret_cast<const float4*>(x + i);
        float4 b = *reinterpret_cast<const float4*>(x + i + 4);
        us4 o0 = { f2bf(a.x), f2bf(a.y), f2bf(a.z), f2bf(a.w) };
        us4 o1 = { f2bf(b.x), f2bf(b.y), f2bf(b.z), f2bf(b.w) };
        *reinterpret_cast<us4*>(xb + i)     = o0;
        *reinterpret_cast<us4*>(xb + i + 4) = o1;
    } else {
        // ---- transpose+convert weights: src [E][K][N] fp32 -> dst [E][N][K] bf16 ----
        const float* src; unsigned short* dst; int K, N, e, k0, n0;
        if (bid < 10240) {
            int r = bid - 6144; e = r >> 9; int rem = r & 511;
            k0 = (rem & 31) * 32; n0 = (rem >> 5) * 32;
            src = w1; dst = w1t; K = DIN; N = DH;
        } else {
            int r = bid - 10240; e = r >> 9; int rem = r & 511;
            k0 = (rem & 15) * 32; n0 = (rem >> 4) * 32;
            src = w2; dst = w2t; K = DH; N = DIN;
        }
        int tx = tid & 31, ty = tid >> 5;
        const float* s = src + ((size_t)e * K + k0) * N + n0;
#pragma unroll
        for (int r2 = 0; r2 < 32; r2 += 8) tile[ty + r2][tx] = s[(size_t)(ty + r2) * N + tx];
        __syncthreads();
        unsigned short* d = dst + ((size_t)e * N + n0) * K + k0;
#pragma unroll
        for (int r2 = 0; r2 < 32; r2 += 8) d[(size_t)(ty + r2) * K + tx] = f2bf(tile[tx][ty + r2]);
    }
}

// ---------------- routing: histogram + 128-aligned prefix + padded build ----------------
__global__ __launch_bounds__(1024) void route_kernel(
    const int2* __restrict__ tokexp, const float2* __restrict__ gpair,
    int* __restrict__ base,
    int* __restrict__ tok_list, float* __restrict__ gate_list,
    int* __restrict__ slot0, int* __restrict__ slot1)
{
    int e = blockIdx.x;
    int tid = threadIdx.x;
    int wave = tid >> 6, lane = tid & 63;
    __shared__ int hist[NE];
    __shared__ int wsum[16];
    __shared__ int running;

    if (tid < NE) hist[tid] = 0;
    __syncthreads();

    // full histogram (every block computes all 8 counts)
    int lc[NE];
#pragma unroll
    for (int j = 0; j < NE; ++j) lc[j] = 0;
#pragma unroll
    for (int r = 0; r < TT / 1024; ++r) {
        int2 te = tokexp[r * 1024 + tid];
#pragma unroll
        for (int j = 0; j < NE; ++j) lc[j] += (te.x == j ? 1 : 0) + (te.y == j ? 1 : 0);
    }
#pragma unroll
    for (int j = 0; j < NE; ++j) {
        int v = lc[j];
#pragma unroll
        for (int m = 1; m < 64; m <<= 1) v += __shfl_xor(v, m);
        if (lane == 0) atomicAdd(&hist[j], v);
    }
    __syncthreads();

    // 128-aligned prefix (identical in every block)
    int basep[NE + 1];
    basep[0] = 0;
#pragma unroll
    for (int j = 0; j < NE; ++j) basep[j + 1] = basep[j] + ((hist[j] + 127) & ~127);

    if (tid == 0) {
        base[e] = basep[e];
        if (e == 0) base[NE] = basep[NE];
        running = basep[e];
    }
    __syncthreads();

    int myb = basep[e];
    int cnt_e = hist[e];
#pragma unroll 1
    for (int r = 0; r < TT / 1024; ++r) {
        int t = r * 1024 + tid;
        int2 te = tokexp[t];
        float2 g = gpair[t];
        bool f0 = (te.x == e), f1 = (te.y == e);
        bool f = f0 || f1;
        unsigned long long mask = __ballot(f);
        int mypos = __popcll(mask & ((1ull << lane) - 1ull));
        if (lane == 0) wsum[wave] = __popcll(mask);
        __syncthreads();
        int off = 0, total = 0;
        for (int w = 0; w < 16; ++w) {
            int c = wsum[w];
            if (w < wave) off += c;
            total += c;
        }
        int pos = running + off + mypos;
        if (f) {
            tok_list[pos]  = t;
            gate_list[pos] = f0 ? g.x : g.y;
            if (f0) slot0[t] = pos; else slot1[t] = pos;
        }
        __syncthreads();
        if (tid == 0) running += total;
        __syncthreads();
    }

    // pad slots: token 0 with gate 0 (safe rows, zero contribution; never read by combine)
    int padn = ((cnt_e + 127) & ~127) - cnt_e;
    if (tid < padn) {
        tok_list[myb + cnt_e + tid]  = 0;
        gate_list[myb + cnt_e + tid] = 0.0f;
    }
}

// ---------------- GEMM1: h = gelu(gather(xb) @ w1t^T), BK=64, double-buffered -----------
__global__ __launch_bounds__(256) void gemm1_kernel(
    const unsigned short* __restrict__ xb, const unsigned short* __restrict__ w1t,
    const int* __restrict__ base,
    const int* __restrict__ tok_list, unsigned short* __restrict__ h)
{
    int bv[NE + 1];
#pragma unroll
    for (int i = 0; i <= NE; ++i) bv[i] = base[i];
    int g0 = blockIdx.x * 128;
    if (g0 >= bv[NE]) return;
    int e = 0;
#pragma unroll
    for (int i = 1; i < NE; ++i) if (g0 >= bv[i]) e = i;

    int n0 = blockIdx.y * 128;

    __shared__ __align__(16) char smem[65536];   // 2 buffers x [A 16K | B 16K]

    int tid = threadIdx.x;
    int w = tid >> 6, lane = tid & 63;
    int wm = w & 1, wn = w >> 1;
    int mcol = lane & 15;
    int kq = (lane >> 4) * 8;

    int ra0 = tok_list[g0 + (2 * w + 0) * 16 + mcol];
    int ra1 = tok_list[g0 + (2 * w + 1) * 16 + mcol];

    const unsigned short* w1e = w1t + (size_t)e * DH * DIN;
    const unsigned short* pa0 = xb + (size_t)ra0 * DIN + kq;
    const unsigned short* pa1 = xb + (size_t)ra1 * DIN + kq;
    const unsigned short* pb0 = w1e + (size_t)(n0 + (2 * w + 0) * 16 + mcol) * DIN + kq;
    const unsigned short* pb1 = w1e + (size_t)(n0 + (2 * w + 1) * 16 + mcol) * DIN + kq;

    int d0 = (2 * w + 0) * 1024;
    int d1 = (2 * w + 1) * 1024;

#define STAGE1(buf, koff) do { \
    async_copy16(pa0 + (koff),      (buf) + d0); \
    async_copy16(pa1 + (koff),      (buf) + d1); \
    async_copy16(pa0 + (koff) + 32, (buf) + 8192  + d0); \
    async_copy16(pa1 + (koff) + 32, (buf) + 8192  + d1); \
    async_copy16(pb0 + (koff),      (buf) + 16384 + d0); \
    async_copy16(pb1 + (koff),      (buf) + 16384 + d1); \
    async_copy16(pb0 + (koff) + 32, (buf) + 24576 + d0); \
    async_copy16(pb1 + (koff) + 32, (buf) + 24576 + d1); \
} while (0)

    f32x4 acc[4][4];
#pragma unroll
    for (int i = 0; i < 4; i++)
#pragma unroll
        for (int j = 0; j < 4; j++) acc[i][j] = {0.f, 0.f, 0.f, 0.f};

    char* cur = smem;
    char* nxt = smem + 32768;

    STAGE1(cur, 0);
    __syncthreads();

    const int NT = DIN / 64;               // 16
    for (int t = 0; t < NT; ++t) {
        if (t + 1 < NT) STAGE1(nxt, (t + 1) * 64);
#pragma unroll
        for (int half = 0; half < 2; ++half) {
            const char* cb = cur + half * 8192;
            short8 af[4], bfr[4];
#pragma unroll
            for (int mt = 0; mt < 4; ++mt)
                af[mt] = *reinterpret_cast<const short8*>(cb + (wm * 4 + mt) * 1024 + lane * 16);
#pragma unroll
            for (int nt = 0; nt < 4; ++nt)
                bfr[nt] = *reinterpret_cast<const short8*>(cb + 16384 + (wn * 4 + nt) * 1024 + lane * 16);
#pragma unroll
            for (int mt = 0; mt < 4; ++mt)
#pragma unroll
                for (int nt = 0; nt < 4; ++nt)
                    acc[mt][nt] = __builtin_amdgcn_mfma_f32_16x16x32_bf16(af[mt], bfr[nt], acc[mt][nt], 0, 0, 0);
        }
        __syncthreads();
        char* tmp = cur; cur = nxt; nxt = tmp;
    }
#undef STAGE1

#pragma unroll
    for (int mt = 0; mt < 4; ++mt) {
        int rbase = (wm * 4 + mt) * 16 + ((lane >> 4) * 4);
#pragma unroll
        for (int r = 0; r < 4; ++r) {
            int row = rbase + r;
#pragma unroll
            for (int nt = 0; nt < 4; ++nt) {
                float g = gelu_erf(acc[mt][nt][r]);
                int col = n0 + (wn * 4 + nt) * 16 + mcol;
                h[(size_t)(g0 + row) * DH + col] = f2bf(g);
            }
        }
    }
}

// ---------------- GEMM2: y = gate * (h @ w2t^T), bf16, BK=64, double-buffered -----------
__global__ __launch_bounds__(256) void gemm2_kernel(
    const unsigned short* __restrict__ h, const unsigned short* __restrict__ w2t,
    const int* __restrict__ base,
    const float* __restrict__ gate_list, unsigned short* __restrict__ y)
{
    int bv[NE + 1];
#pragma unroll
    for (int i = 0; i <= NE; ++i) bv[i] = base[i];
    int g0 = blockIdx.x * 128;
    if (g0 >= bv[NE]) return;
    int e = 0;
#pragma unroll
    for (int i = 1; i < NE; ++i) if (g0 >= bv[i]) e = i;

    int n0 = blockIdx.y * 128;

    __shared__ __align__(16) char smem[65536];

    int tid = threadIdx.x;
    int w = tid >> 6, lane = tid & 63;
    int wm = w & 1, wn = w >> 1;
    int mcol = lane & 15;
    int kq = (lane >> 4) * 8;

    const unsigned short* w2e = w2t + (size_t)e * DIN * DH;
    const unsigned short* pa0 = h + (size_t)(g0 + (2 * w + 0) * 16 + mcol) * DH + kq;
    const unsigned short* pa1 = h + (size_t)(g0 + (2 * w + 1) * 16 + mcol) * DH + kq;
    const unsigned short* pb0 = w2e + (size_t)(n0 + (2 * w + 0) * 16 + mcol) * DH + kq;
    const unsigned short* pb1 = w2e + (size_t)(n0 + (2 * w + 1) * 16 + mcol) * DH + kq;

    int d0 = (2 * w + 0) * 1024;
    int d1 = (2 * w + 1) * 1024;

#define STAGE2(buf, koff) do { \
    async_copy16(pa0 + (koff),      (buf) + d0); \
    async_copy16(pa1 + (koff),      (buf) + d1); \
    async_copy16(pa0 + (koff) + 32, (buf) + 8192  + d0); \
    async_copy16(pa1 + (koff) + 32, (buf) + 8192  + d1); \
    async_copy16(pb0 + (koff),      (buf) + 16384 + d0); \
    async_copy16(pb1 + (koff),      (buf) + 16384 + d1); \
    async_copy16(pb0 + (koff) + 32, (buf) + 24576 + d0); \
    async_copy16(pb1 + (koff) + 32, (buf) + 24576 + d1); \
} while (0)

    f32x4 acc[4][4];
#pragma unroll
    for (int i = 0; i < 4; i++)
#pragma unroll
        for (int j = 0; j < 4; j++) acc[i][j] = {0.f, 0.f, 0.f, 0.f};

    char* cur = smem;
    char* nxt = smem + 32768;

    STAGE2(cur, 0);
    __syncthreads();

    const int NT = DH / 64;                // 8
    for (int t = 0; t < NT; ++t) {
        if (t + 1 < NT) STAGE2(nxt, (t + 1) * 64);
#pragma unroll
        for (int half = 0; half < 2; ++half) {
            const char* cb = cur + half * 8192;
            short8 af[4], bfr[4];
#pragma unroll
            for (int mt = 0; mt < 4; ++mt)
                af[mt] = *reinterpret_cast<const short8*>(cb + (wm * 4 + mt) * 1024 + lane * 16);
#pragma unroll
            for (int nt = 0; nt < 4; ++nt)
                bfr[nt] = *reinterpret_cast<const short8*>(cb + 16384 + (wn * 4 + nt) * 1024 + lane * 16);
#pragma unroll
            for (int mt = 0; mt < 4; ++mt)
#pragma unroll
                for (int nt = 0; nt < 4; ++nt)
                    acc[mt][nt] = __builtin_amdgcn_mfma_f32_16x16x32_bf16(af[mt], bfr[nt], acc[mt][nt], 0, 0, 0);
        }
        __syncthreads();
        char* tmp = cur; cur = nxt; nxt = tmp;
    }
#undef STAGE2

#pragma unroll
    for (int mt = 0; mt < 4; ++mt) {
        int rbase = (wm * 4 + mt) * 16 + ((lane >> 4) * 4);
#pragma unroll
        for (int r = 0; r < 4; ++r) {
            int row = rbase + r;
            float g = gate_list[g0 + row];
#pragma unroll
            for (int nt = 0; nt < 4; ++nt) {
                int col = n0 + (wn * 4 + nt) * 16 + mcol;
                y[(size_t)(g0 + row) * DIN + col] = f2bf(acc[mt][nt][r] * g);
            }
        }
    }
}

// ---------------- combine: out[t] = y[slot0[t]] + y[slot1[t]], 4 tokens/block -----------
__global__ __launch_bounds__(256) void combine_kernel(
    const unsigned short* __restrict__ y,
    const int* __restrict__ slot0, const int* __restrict__ slot1,
    float* __restrict__ out)
{
    int c = threadIdx.x * 4;
#pragma unroll
    for (int r = 0; r < 4; ++r) {
        int t = blockIdx.x * 4 + r;
        const unsigned short* y0 = y + (size_t)slot0[t] * DIN + c;
        const unsigned short* y1 = y + (size_t)slot1[t] * DIN + c;
        us4 u0 = *reinterpret_cast<const us4*>(y0);
        us4 u1 = *reinterpret_cast<const us4*>(y1);
        float4 o;
        o.x = bf2f(u0.x) + bf2f(u1.x);
        o.y = bf2f(u0.y) + bf2f(u1.y);
        o.z = bf2f(u0.z) + bf2f(u1.z);
        o.w = bf2f(u0.w) + bf2f(u1.w);
        *reinterpret_cast<float4*>(out + (size_t)t * DIN + c) = o;
    }
}

extern "C" void kernel_launch(void* const* d_in, const int* in_sizes, int n_in,
                              void* d_out, int out_size, void* d_ws, size_t ws_size,
                              hipStream_t stream) {
    const float* x  = (const float*)d_in[0];
    const float* Q  = (const float*)d_in[1];
    const float* K  = (const float*)d_in[2];
    const float* w1 = (const float*)d_in[3];
    const float* w2 = (const float*)d_in[4];
    float* out = (float*)d_out;

    char* ws = (char*)d_ws;
    int*    base      = (int*)(ws + OFF_BASE);
    int2*   tokexp    = (int2*)(ws + OFF_TOKEXP);
    float2* gpair     = (float2*)(ws + OFF_GPAIR);
    int*    slot0     = (int*)(ws + OFF_SLOT0);
    int*    slot1     = (int*)(ws + OFF_SLOT1);
    int*    tok_list  = (int*)(ws + OFF_TOK);
    float*  gate_list = (float*)(ws + OFF_GATE);
    unsigned short* xb  = (unsigned short*)(ws + OFF_XB);
    unsigned short* w1t = (unsigned short*)(ws + OFF_W1T);
    unsigned short* w2t = (unsigned short*)(ws + OFF_W2T);
    unsigned short* h   = (unsigned short*)(ws + OFF_H);
    unsigned short* y   = (unsigned short*)(ws + OFF_Y);

    prep_kernel<<<14336, 256, 0, stream>>>(x, w1, w2, Q, K, xb, w1t, w2t, tokexp, gpair);
    route_kernel<<<NE, 1024, 0, stream>>>(tokexp, gpair, base, tok_list, gate_list, slot0, slot1);
    gemm1_kernel<<<dim3(MT_MAX, DH / 128), 256, 0, stream>>>(xb, w1t, base, tok_list, h);
    gemm2_kernel<<<dim3(MT_MAX, DIN / 128), 256, 0, stream>>>(h, w2t, base, gate_list, y);
    combine_kernel<<<TT / 4, 256, 0, stream>>>(y, slot0, slot1, out);
}

// Round 4
// 541.127 us; speedup vs baseline: 1.2116x; 1.0191x over previous
//
#include <hip/hip_runtime.h>
#include <math.h>

#define TT 8192   // tokens = B*P
#define NE 8      // experts
#define DIN 1024  // input size
#define DH 512    // hidden size
#define MT_MAX 136  // ceil(2*TT/128) + NE  (padded m-tiles upper bound)

typedef __attribute__((ext_vector_type(8))) short short8;   // 8 bf16 = 4 VGPRs
typedef __attribute__((ext_vector_type(4))) float f32x4;
typedef __attribute__((ext_vector_type(4))) unsigned short us4;

// ---------------- workspace layout (bytes) ----------------
static const size_t NSLOT      = (size_t)(2 * TT + NE * 128);            // padded slots
static const size_t OFF_BASE   = 0;                                      // int[9] padded prefix
static const size_t OFF_TOKEXP = 256;                                    // int2[TT]
static const size_t OFF_GPAIR  = OFF_TOKEXP + (size_t)TT * 8;            // float2[TT]
static const size_t OFF_SLOT0  = OFF_GPAIR  + (size_t)TT * 8;            // int[TT]
static const size_t OFF_SLOT1  = OFF_SLOT0  + (size_t)TT * 4;            // int[TT]
static const size_t OFF_TOK    = OFF_SLOT1  + (size_t)TT * 4;            // int[NSLOT]
static const size_t OFF_GATE   = OFF_TOK    + NSLOT * 4;                 // float[NSLOT]
static const size_t OFF_XB     = OFF_GATE   + NSLOT * 4;                 // bf16[TT][DIN]
static const size_t OFF_W1T    = OFF_XB     + (size_t)TT * DIN * 2;      // bf16[NE][DH][DIN]
static const size_t OFF_W2T    = OFF_W1T    + (size_t)NE * DH * DIN * 2; // bf16[NE][DIN][DH]
static const size_t OFF_H      = OFF_W2T    + (size_t)NE * DIN * DH * 2; // bf16[NSLOT][DH]
static const size_t OFF_Y      = OFF_H      + NSLOT * DH * 2;            // bf16[NSLOT][DIN]

__device__ __forceinline__ unsigned short f2bf(float f) {
    union { float f; unsigned u; } v; v.f = f;
    unsigned r = (v.u + 0x7fffu + ((v.u >> 16) & 1u)) >> 16;
    return (unsigned short)r;
}
__device__ __forceinline__ float bf2f(unsigned short u) {
    union { unsigned u; float f; } v; v.u = ((unsigned)u) << 16;
    return v.f;
}
__device__ __forceinline__ void async_copy16(const void* g, void* l) {
    __builtin_amdgcn_global_load_lds(
        (const __attribute__((address_space(1))) void*)g,
        (__attribute__((address_space(3))) void*)l, 16, 0, 0);
}

// exact-erf GELU via Abramowitz-Stegun 7.1.26 (|err| <= 1.5e-7, << bf16 ulp)
__device__ __forceinline__ float gelu_erf(float u) {
    float z  = 0.70710678118f * u;
    float az = fabsf(z);
    float t  = __builtin_amdgcn_rcpf(__builtin_fmaf(0.3275911f, az, 1.0f));
    float p  = t * (0.254829592f + t * (-0.284496736f + t * (1.421413741f +
               t * (-1.453152027f + t * 1.061405429f))));
    float e2 = exp2f(-1.4426950408889634f * az * az);
    float er = __builtin_fmaf(-p, e2, 1.0f);
    er = copysignf(er, z);
    return 0.5f * u * (1.0f + er);
}

// ---------------- fused prep: gate | convert x | transpose w1/w2 ------------------------
// grid: [0,2048) gate | [2048,6144) x | [6144,10240) w1 | [10240,14336) w2
__global__ __launch_bounds__(256) void prep_kernel(
    const float* __restrict__ x, const float* __restrict__ w1, const float* __restrict__ w2,
    const float* __restrict__ Q, const float* __restrict__ Kc,
    unsigned short* __restrict__ xb, unsigned short* __restrict__ w1t,
    unsigned short* __restrict__ w2t,
    int2* __restrict__ tokexp, float2* __restrict__ gpair)
{
    __shared__ float tile[32][33];
    int bid = blockIdx.x;
    int tid = threadIdx.x;

    if (bid < 2048) {
        // ---- gating: one wave per token (long-pole blocks dispatched first) ----
        int wave = tid >> 6, lane = tid & 63;
        int t = bid * 4 + wave;
        const float4* q4 = reinterpret_cast<const float4*>(Q + (size_t)t * DIN);
        const float4* k4 = reinterpret_cast<const float4*>(Kc + (size_t)t * NE * DIN);
        float4 q[4];
#pragma unroll
        for (int j = 0; j < 4; ++j) q[j] = q4[j * 64 + lane];
        float part[NE];
#pragma unroll
        for (int e = 0; e < NE; ++e) {
            float s = 0.0f;
#pragma unroll
            for (int j = 0; j < 4; ++j) {
                float4 kv = k4[e * 256 + j * 64 + lane];
                s += q[j].x * kv.x + q[j].y * kv.y + q[j].z * kv.z + q[j].w * kv.w;
            }
            part[e] = s;
        }
#pragma unroll
        for (int e = 0; e < NE; ++e) {
#pragma unroll
            for (int m = 1; m < 64; m <<= 1) part[e] += __shfl_xor(part[e], m);
        }
        if (lane == 0) {
            float s[NE];
#pragma unroll
            for (int e = 0; e < NE; ++e) {
                float v = part[e] * 0.03125f;
                if (isnan(v)) v = 0.0f;
                else if (isinf(v)) v = (v > 0.0f) ? 20.0f : -20.0f;
                s[e] = v;
            }
            float m = s[0];
            for (int e = 1; e < NE; ++e) m = fmaxf(m, s[e]);
            float p[NE]; float sum = 0.0f;
            for (int e = 0; e < NE; ++e) { p[e] = expf(s[e] - m); sum += p[e]; }
            float inv = 1.0f / sum;
            for (int e = 0; e < NE; ++e) p[e] *= inv;
            int i0 = 0;
            for (int e = 1; e < NE; ++e) if (p[e] > p[i0]) i0 = e;
            int i1 = (i0 == 0) ? 1 : 0;
            for (int e = 0; e < NE; ++e) if (e != i0 && p[e] > p[i1]) i1 = e;
            float denom = p[i0] + p[i1] + 1e-6f;
            tokexp[t] = make_int2(i0, i1);
            gpair[t]  = make_float2(p[i0] / denom, p[i1] / denom);
        }
    } else if (bid < 6144) {
        // ---- convert x: fp32 -> bf16, 8 elems/thread ----
        size_t i = ((size_t)(bid - 2048) * 256 + tid) * 8;
        float4 a = *reinterpret_cast<const float4*>(x + i);
        float4 b = *reinterpret_cast<const float4*>(x + i + 4);
        us4 o0 = { f2bf(a.x), f2bf(a.y), f2bf(a.z), f2bf(a.w) };
        us4 o1 = { f2bf(b.x), f2bf(b.y), f2bf(b.z), f2bf(b.w) };
        *reinterpret_cast<us4*>(xb + i)     = o0;
        *reinterpret_cast<us4*>(xb + i + 4) = o1;
    } else {
        // ---- transpose+convert weights: src [E][K][N] fp32 -> dst [E][N][K] bf16 ----
        const float* src; unsigned short* dst; int K, N, e, k0, n0;
        if (bid < 10240) {
            int r = bid - 6144; e = r >> 9; int rem = r & 511;
            k0 = (rem & 31) * 32; n0 = (rem >> 5) * 32;
            src = w1; dst = w1t; K = DIN; N = DH;
        } else {
            int r = bid - 10240; e = r >> 9; int rem = r & 511;
            k0 = (rem & 15) * 32; n0 = (rem >> 4) * 32;
            src = w2; dst = w2t; K = DH; N = DIN;
        }
        int tx = tid & 31, ty = tid >> 5;
        const float* s = src + ((size_t)e * K + k0) * N + n0;
#pragma unroll
        for (int r2 = 0; r2 < 32; r2 += 8) tile[ty + r2][tx] = s[(size_t)(ty + r2) * N + tx];
        __syncthreads();
        unsigned short* d = dst + ((size_t)e * N + n0) * K + k0;
#pragma unroll
        for (int r2 = 0; r2 < 32; r2 += 8) d[(size_t)(ty + r2) * K + tx] = f2bf(tile[tx][ty + r2]);
    }
}

// ---------------- routing: histogram + 128-aligned prefix + padded build ----------------
__global__ __launch_bounds__(1024) void route_kernel(
    const int2* __restrict__ tokexp, const float2* __restrict__ gpair,
    int* __restrict__ base,
    int* __restrict__ tok_list, float* __restrict__ gate_list,
    int* __restrict__ slot0, int* __restrict__ slot1)
{
    int e = blockIdx.x;
    int tid = threadIdx.x;
    int wave = tid >> 6, lane = tid & 63;
    __shared__ int hist[NE];
    __shared__ int wsum[16];
    __shared__ int running;

    if (tid < NE) hist[tid] = 0;
    __syncthreads();

    // full histogram (every block computes all 8 counts)
    int lc[NE];
#pragma unroll
    for (int j = 0; j < NE; ++j) lc[j] = 0;
#pragma unroll
    for (int r = 0; r < TT / 1024; ++r) {
        int2 te = tokexp[r * 1024 + tid];
#pragma unroll
        for (int j = 0; j < NE; ++j) lc[j] += (te.x == j ? 1 : 0) + (te.y == j ? 1 : 0);
    }
#pragma unroll
    for (int j = 0; j < NE; ++j) {
        int v = lc[j];
#pragma unroll
        for (int m = 1; m < 64; m <<= 1) v += __shfl_xor(v, m);
        if (lane == 0) atomicAdd(&hist[j], v);
    }
    __syncthreads();

    // 128-aligned prefix (identical in every block)
    int basep[NE + 1];
    basep[0] = 0;
#pragma unroll
    for (int j = 0; j < NE; ++j) basep[j + 1] = basep[j] + ((hist[j] + 127) & ~127);

    if (tid == 0) {
        base[e] = basep[e];
        if (e == 0) base[NE] = basep[NE];
        running = basep[e];
    }
    __syncthreads();

    int myb = basep[e];
    int cnt_e = hist[e];
#pragma unroll 1
    for (int r = 0; r < TT / 1024; ++r) {
        int t = r * 1024 + tid;
        int2 te = tokexp[t];
        float2 g = gpair[t];
        bool f0 = (te.x == e), f1 = (te.y == e);
        bool f = f0 || f1;
        unsigned long long mask = __ballot(f);
        int mypos = __popcll(mask & ((1ull << lane) - 1ull));
        if (lane == 0) wsum[wave] = __popcll(mask);
        __syncthreads();
        int off = 0, total = 0;
        for (int w = 0; w < 16; ++w) {
            int c = wsum[w];
            if (w < wave) off += c;
            total += c;
        }
        int pos = running + off + mypos;
        if (f) {
            tok_list[pos]  = t;
            gate_list[pos] = f0 ? g.x : g.y;
            if (f0) slot0[t] = pos; else slot1[t] = pos;
        }
        __syncthreads();
        if (tid == 0) running += total;
        __syncthreads();
    }

    // pad slots: token 0 with gate 0 (safe rows, zero contribution; never read by combine)
    int padn = ((cnt_e + 127) & ~127) - cnt_e;
    if (tid < padn) {
        tok_list[myb + cnt_e + tid]  = 0;
        gate_list[myb + cnt_e + tid] = 0.0f;
    }
}

// ---------------- GEMM1: h = gelu(gather(xb) @ w1t^T) ----------------------------------
// BK=32, 4-deep LDS ring (4 x 16KB), counted vmcnt: loads stay in flight across barriers
__global__ __launch_bounds__(256) void gemm1_kernel(
    const unsigned short* __restrict__ xb, const unsigned short* __restrict__ w1t,
    const int* __restrict__ base,
    const int* __restrict__ tok_list, unsigned short* __restrict__ h)
{
    int bv[NE + 1];
#pragma unroll
    for (int i = 0; i <= NE; ++i) bv[i] = base[i];
    int g0 = blockIdx.x * 128;
    if (g0 >= bv[NE]) return;
    int e = 0;
#pragma unroll
    for (int i = 1; i < NE; ++i) if (g0 >= bv[i]) e = i;

    int n0 = blockIdx.y * 128;

    __shared__ __align__(16) char smem[65536];   // 4 ring buffers x [A 8K | B 8K]

    int tid = threadIdx.x;
    int w = tid >> 6, lane = tid & 63;
    int wm = w & 1, wn = w >> 1;
    int mcol = lane & 15;
    int kq = (lane >> 4) * 8;

    int ra0 = tok_list[g0 + (2 * w + 0) * 16 + mcol];
    int ra1 = tok_list[g0 + (2 * w + 1) * 16 + mcol];

    const unsigned short* w1e = w1t + (size_t)e * DH * DIN;
    const unsigned short* pa0 = xb + (size_t)ra0 * DIN + kq;
    const unsigned short* pa1 = xb + (size_t)ra1 * DIN + kq;
    const unsigned short* pb0 = w1e + (size_t)(n0 + (2 * w + 0) * 16 + mcol) * DIN + kq;
    const unsigned short* pb1 = w1e + (size_t)(n0 + (2 * w + 1) * 16 + mcol) * DIN + kq;

    int d0 = (2 * w + 0) * 1024;
    int d1 = (2 * w + 1) * 1024;

#define STAGE1(buf, koff) do { \
    async_copy16(pa0 + (koff), (buf) + d0); \
    async_copy16(pa1 + (koff), (buf) + d1); \
    async_copy16(pb0 + (koff), (buf) + 8192 + d0); \
    async_copy16(pb1 + (koff), (buf) + 8192 + d1); \
} while (0)

    f32x4 acc[4][4];
#pragma unroll
    for (int i = 0; i < 4; i++)
#pragma unroll
        for (int j = 0; j < 4; j++) acc[i][j] = {0.f, 0.f, 0.f, 0.f};

    // prologue: fill 3 ring slots (12 loads in flight)
    STAGE1(smem + 0 * 16384, 0);
    STAGE1(smem + 1 * 16384, 32);
    STAGE1(smem + 2 * 16384, 64);

    const int NT = DIN / 32;               // 32
    for (int t = 0; t < NT; ++t) {
        // wait: own share of ring slot t landed; keep up to 8 newer loads in flight
        if (t < NT - 2)       asm volatile("s_waitcnt vmcnt(8)" ::: "memory");
        else if (t == NT - 2) asm volatile("s_waitcnt vmcnt(4)" ::: "memory");
        else                  asm volatile("s_waitcnt vmcnt(0)" ::: "memory");
        __builtin_amdgcn_sched_barrier(0);
        __builtin_amdgcn_s_barrier();      // all waves' shares landed; slot t-1 reads retired
        __builtin_amdgcn_sched_barrier(0);
        if (t + 3 < NT) STAGE1(smem + ((t + 3) & 3) * 16384, (t + 3) * 32);

        const char* cb = smem + (t & 3) * 16384;
        short8 af[4], bfr[4];
#pragma unroll
        for (int mt = 0; mt < 4; ++mt)
            af[mt] = *reinterpret_cast<const short8*>(cb + (wm * 4 + mt) * 1024 + lane * 16);
#pragma unroll
        for (int nt = 0; nt < 4; ++nt)
            bfr[nt] = *reinterpret_cast<const short8*>(cb + 8192 + (wn * 4 + nt) * 1024 + lane * 16);
#pragma unroll
        for (int mt = 0; mt < 4; ++mt)
#pragma unroll
            for (int nt = 0; nt < 4; ++nt)
                acc[mt][nt] = __builtin_amdgcn_mfma_f32_16x16x32_bf16(af[mt], bfr[nt], acc[mt][nt], 0, 0, 0);
        __builtin_amdgcn_sched_barrier(0); // keep this step's reads+MFMA before next barrier
    }
#undef STAGE1

#pragma unroll
    for (int mt = 0; mt < 4; ++mt) {
        int rbase = (wm * 4 + mt) * 16 + ((lane >> 4) * 4);
#pragma unroll
        for (int r = 0; r < 4; ++r) {
            int row = rbase + r;
#pragma unroll
            for (int nt = 0; nt < 4; ++nt) {
                float g = gelu_erf(acc[mt][nt][r]);
                int col = n0 + (wn * 4 + nt) * 16 + mcol;
                h[(size_t)(g0 + row) * DH + col] = f2bf(g);
            }
        }
    }
}

// ---------------- GEMM2: y = gate * (h @ w2t^T), same 4-deep ring schedule --------------
__global__ __launch_bounds__(256) void gemm2_kernel(
    const unsigned short* __restrict__ h, const unsigned short* __restrict__ w2t,
    const int* __restrict__ base,
    const float* __restrict__ gate_list, unsigned short* __restrict__ y)
{
    int bv[NE + 1];
#pragma unroll
    for (int i = 0; i <= NE; ++i) bv[i] = base[i];
    int g0 = blockIdx.x * 128;
    if (g0 >= bv[NE]) return;
    int e = 0;
#pragma unroll
    for (int i = 1; i < NE; ++i) if (g0 >= bv[i]) e = i;

    int n0 = blockIdx.y * 128;

    __shared__ __align__(16) char smem[65536];

    int tid = threadIdx.x;
    int w = tid >> 6, lane = tid & 63;
    int wm = w & 1, wn = w >> 1;
    int mcol = lane & 15;
    int kq = (lane >> 4) * 8;

    const unsigned short* w2e = w2t + (size_t)e * DIN * DH;
    const unsigned short* pa0 = h + (size_t)(g0 + (2 * w + 0) * 16 + mcol) * DH + kq;
    const unsigned short* pa1 = h + (size_t)(g0 + (2 * w + 1) * 16 + mcol) * DH + kq;
    const unsigned short* pb0 = w2e + (size_t)(n0 + (2 * w + 0) * 16 + mcol) * DH + kq;
    const unsigned short* pb1 = w2e + (size_t)(n0 + (2 * w + 1) * 16 + mcol) * DH + kq;

    int d0 = (2 * w + 0) * 1024;
    int d1 = (2 * w + 1) * 1024;

#define STAGE2(buf, koff) do { \
    async_copy16(pa0 + (koff), (buf) + d0); \
    async_copy16(pa1 + (koff), (buf) + d1); \
    async_copy16(pb0 + (koff), (buf) + 8192 + d0); \
    async_copy16(pb1 + (koff), (buf) + 8192 + d1); \
} while (0)

    f32x4 acc[4][4];
#pragma unroll
    for (int i = 0; i < 4; i++)
#pragma unroll
        for (int j = 0; j < 4; j++) acc[i][j] = {0.f, 0.f, 0.f, 0.f};

    STAGE2(smem + 0 * 16384, 0);
    STAGE2(smem + 1 * 16384, 32);
    STAGE2(smem + 2 * 16384, 64);

    const int NT = DH / 32;                // 16
    for (int t = 0; t < NT; ++t) {
        if (t < NT - 2)       asm volatile("s_waitcnt vmcnt(8)" ::: "memory");
        else if (t == NT - 2) asm volatile("s_waitcnt vmcnt(4)" ::: "memory");
        else                  asm volatile("s_waitcnt vmcnt(0)" ::: "memory");
        __builtin_amdgcn_sched_barrier(0);
        __builtin_amdgcn_s_barrier();
        __builtin_amdgcn_sched_barrier(0);
        if (t + 3 < NT) STAGE2(smem + ((t + 3) & 3) * 16384, (t + 3) * 32);

        const char* cb = smem + (t & 3) * 16384;
        short8 af[4], bfr[4];
#pragma unroll
        for (int mt = 0; mt < 4; ++mt)
            af[mt] = *reinterpret_cast<const short8*>(cb + (wm * 4 + mt) * 1024 + lane * 16);
#pragma unroll
        for (int nt = 0; nt < 4; ++nt)
            bfr[nt] = *reinterpret_cast<const short8*>(cb + 8192 + (wn * 4 + nt) * 1024 + lane * 16);
#pragma unroll
        for (int mt = 0; mt < 4; ++mt)
#pragma unroll
            for (int nt = 0; nt < 4; ++nt)
                acc[mt][nt] = __builtin_amdgcn_mfma_f32_16x16x32_bf16(af[mt], bfr[nt], acc[mt][nt], 0, 0, 0);
        __builtin_amdgcn_sched_barrier(0);
    }
#undef STAGE2

#pragma unroll
    for (int mt = 0; mt < 4; ++mt) {
        int rbase = (wm * 4 + mt) * 16 + ((lane >> 4) * 4);
#pragma unroll
        for (int r = 0; r < 4; ++r) {
            int row = rbase + r;
            float g = gate_list[g0 + row];
#pragma unroll
            for (int nt = 0; nt < 4; ++nt) {
                int col = n0 + (wn * 4 + nt) * 16 + mcol;
                y[(size_t)(g0 + row) * DIN + col] = f2bf(acc[mt][nt][r] * g);
            }
        }
    }
}

// ---------------- combine: out[t] = y[slot0[t]] + y[slot1[t]], 4 tokens/block -----------
__global__ __launch_bounds__(256) void combine_kernel(
    const unsigned short* __restrict__ y,
    const int* __restrict__ slot0, const int* __restrict__ slot1,
    float* __restrict__ out)
{
    int c = threadIdx.x * 4;
#pragma unroll
    for (int r = 0; r < 4; ++r) {
        int t = blockIdx.x * 4 + r;
        const unsigned short* y0 = y + (size_t)slot0[t] * DIN + c;
        const unsigned short* y1 = y + (size_t)slot1[t] * DIN + c;
        us4 u0 = *reinterpret_cast<const us4*>(y0);
        us4 u1 = *reinterpret_cast<const us4*>(y1);
        float4 o;
        o.x = bf2f(u0.x) + bf2f(u1.x);
        o.y = bf2f(u0.y) + bf2f(u1.y);
        o.z = bf2f(u0.z) + bf2f(u1.z);
        o.w = bf2f(u0.w) + bf2f(u1.w);
        *reinterpret_cast<float4*>(out + (size_t)t * DIN + c) = o;
    }
}

extern "C" void kernel_launch(void* const* d_in, const int* in_sizes, int n_in,
                              void* d_out, int out_size, void* d_ws, size_t ws_size,
                              hipStream_t stream) {
    const float* x  = (const float*)d_in[0];
    const float* Q  = (const float*)d_in[1];
    const float* K  = (const float*)d_in[2];
    const float* w1 = (const float*)d_in[3];
    const float* w2 = (const float*)d_in[4];
    float* out = (float*)d_out;

    char* ws = (char*)d_ws;
    int*    base      = (int*)(ws + OFF_BASE);
    int2*   tokexp    = (int2*)(ws + OFF_TOKEXP);
    float2* gpair     = (float2*)(ws + OFF_GPAIR);
    int*    slot0     = (int*)(ws + OFF_SLOT0);
    int*    slot1     = (int*)(ws + OFF_SLOT1);
    int*    tok_list  = (int*)(ws + OFF_TOK);
    float*  gate_list = (float*)(ws + OFF_GATE);
    unsigned short* xb  = (unsigned short*)(ws + OFF_XB);
    unsigned short* w1t = (unsigned short*)(ws + OFF_W1T);
    unsigned short* w2t = (unsigned short*)(ws + OFF_W2T);
    unsigned short* h   = (unsigned short*)(ws + OFF_H);
    unsigned short* y   = (unsigned short*)(ws + OFF_Y);

    prep_kernel<<<14336, 256, 0, stream>>>(x, w1, w2, Q, K, xb, w1t, w2t, tokexp, gpair);
    route_kernel<<<NE, 1024, 0, stream>>>(tokexp, gpair, base, tok_list, gate_list, slot0, slot1);
    gemm1_kernel<<<dim3(MT_MAX, DH / 128), 256, 0, stream>>>(xb, w1t, base, tok_list, h);
    gemm2_kernel<<<dim3(MT_MAX, DIN / 128), 256, 0, stream>>>(h, w2t, base, gate_list, y);
    combine_kernel<<<TT / 4, 256, 0, stream>>>(y, slot0, slot1, out);
}